// Round 8
// baseline (242.926 us; speedup 1.0000x reference)
//
#include <hip/hip_runtime.h>

// GRU: B=8192 chains, T=512 steps, IN=5, H=7, fused heads.
// R11: de-mirrored groups. 16-lane group = TWO batches (half h=l>>3), lane
// owns unit j=l&7 of ITS batch: rows r_j,z_j in one pk acc, n_j scalar acc.
// Kills the R4-R10 mirror redundancy (n-matvec computed twice, ror:8 gate
// swap, rv/zv selects). 8 batches/wave -> 1024 waves = 1 wave/SIMD; justified
// (vs R8's failed 1-wave attempt) because issue-cycles/batch drop ~44%:
// R10 = 342 cy/step/SIMD for 8 batches; R11 ~ 196 cy/step/wave for 8.
// 8-wide rotation inside 16-wide DPP (derived+checked both halves):
//   want lane l=8h+j <- h_state[8h + (j-i)&7]
//   ror:i   gives it when j>=i;  ror:(i+8) gives it when j<i
//   (identity ((l-i)&15)^8 == (l-i-8)&15); select via hoisted (j>=i) masks.
// Heads: m0,m1 ride pad-lane (j==7) pk slots, m2 rides pad-lane scalar slot
// (R7 trick, per-half so each batch gets its own); r-head = in-register
// 8-lane reduce: quad_perm 0xB1 (xor1), 0x4E (xor2), row_half_mirror 0x141.
// Head ring (R10 idea, bank-fixed): planes m0@0,m1@40,m2@80,r@120, batch
// stride 140 (mod32=12): write2 banks uniform 2-way (free, m136); flush
// fq=(q%3)*40+q/3 -> 16 distinct banks (R10's *33 was 3-way, 1.7M conflicts).
// Gate pre-scaling (R9, verified): r,z rows by -log2e, n rows by -2log2e.
// x staging (R4): LDS double-buffer, XSTR=84 (mod32=20: 8 slots/wave cover
// all 32 banks exactly, conflict-free b128 broadcast reads).
// TILE=16 steps (LDS budget), 32 batches/block, grid 256 = 1 block/CU.

namespace {
constexpr int Bn = 8192;
constexpr int Tn = 512;
constexpr int INn = 5;
constexpr int Hn = 7;
constexpr int TILE = 16;
constexpr int NTILE = Tn / TILE;         // 32
constexpr int CPT = 4;                   // chunks/tile (4 steps each)
constexpr int BPB = 32;                  // batches per block (16 groups x 2)
constexpr int XSTR = 84;                 // x floats/batch in LDS (80 + 4 pad)
constexpr int RSTR = 140;                // ring dwords/batch
constexpr long long OFF_OR = (long long)Bn * Tn * 3;
constexpr long long OFF_HL = OFF_OR + (long long)Bn * Tn;
constexpr float LOG2E = 1.44269504088896340736f;
}

typedef float v2f __attribute__((ext_vector_type(2)));

__device__ __forceinline__ v2f pk_fma(v2f a, v2f b, v2f c) {
    return __builtin_elementwise_fma(a, b, c);
}
__device__ __forceinline__ v2f splat2(float x) { return (v2f){x, x}; }

template<int CTRL>
__device__ __forceinline__ float dppf(float v) {
    int r = __builtin_amdgcn_update_dpp(0, __builtin_bit_cast(int, v),
                                        CTRL, 0xF, 0xF, true);
    return __builtin_bit_cast(float, r);
}

__global__ __launch_bounds__(256, 1) void gru_fused_kernel(
    const float* __restrict__ x,     // [B, T, IN]
    const float* __restrict__ W_ih,  // [21, 5]
    const float* __restrict__ W_hh,  // [21, 7]
    const float* __restrict__ b_ih,  // [21]
    const float* __restrict__ b_hh,  // [21]
    const float* __restrict__ W_h0,  // [7, 1]
    const float* __restrict__ W_m,   // [3, 7]
    const float* __restrict__ b_m,   // [3]
    const float* __restrict__ W_r,   // [1, 7]
    const float* __restrict__ b_r,   // [1]
    float* __restrict__ out)
{
    __shared__ float lds_x[2][BPB * XSTR];   // 2 x 10.5 KB
    __shared__ float lds_r[BPB * RSTR];      // 17.5 KB head ring

    const int tid  = threadIdx.x;
    const int l    = tid & 15;           // lane in 16-lane group
    const int j    = l & 7;              // hidden unit (7 = pad/head lane)
    const int g    = tid >> 4;           // group in block (0..15)
    const int sm   = tid >> 3;           // batch slot in block (0..31)
    const int b    = blockIdx.x * BPB + sm;
    const bool pad = (j == 7);

    const float kR = -LOG2E;             // sigmoid preact scale (r and z)
    const float kN = -2.0f * LOG2E;      // tanh preact scale (n)

    // ---- rotated weights; lane j: rows r_j (pk.x), z_j (pk.y), n_j (sc) ----
    // pad lane: pk = (W_m row0, W_m row1), scalar = W_m row2 (raw, no scale)
    v2f  wrz[8];
    float wn[8];
    #pragma unroll
    for (int i = 0; i < 8; ++i) {
        const int k = (j - i) & 7;
        if (k < 7) {
            if (pad) {
                wrz[i] = (v2f){W_m[0 * Hn + k], W_m[1 * Hn + k]};
                wn[i]  = W_m[2 * Hn + k];
            } else {
                wrz[i] = (v2f){kR * W_hh[j * Hn + k],
                               kR * W_hh[(Hn + j) * Hn + k]};
                wn[i]  = kN * W_hh[(2 * Hn + j) * Hn + k];
            }
        } else {
            wrz[i] = (v2f){0.0f, 0.0f};
            wn[i]  = 0.0f;
        }
    }
    v2f  wpx[INn];
    float wpn[INn];
    #pragma unroll
    for (int i = 0; i < INn; ++i) {
        wpx[i] = pad ? (v2f){0.0f, 0.0f}
                     : (v2f){kR * W_ih[j * INn + i],
                             kR * W_ih[(Hn + j) * INn + i]};
        wpn[i] = pad ? 0.0f : kN * W_ih[(2 * Hn + j) * INn + i];
    }
    // combined biases: rz acc gets b_ih+b_hh (both outside gates);
    // n: b_hh inside the r-multiply (hidden acc), b_ih outside (input acc)
    const v2f biasRZ = pad ? (v2f){b_m[0], b_m[1]}
                           : (v2f){kR * (b_ih[j] + b_hh[j]),
                                   kR * (b_ih[Hn + j] + b_hh[Hn + j])};
    const float biasNh = pad ? b_m[2] : kN * b_hh[2 * Hn + j];
    const float biasNx = pad ? 0.0f   : kN * b_ih[2 * Hn + j];
    const float wrl = (j < Hn) ? W_r[j] : 0.0f;   // r-head reduce weight
    const float brv = b_r[0];

    // rotation-select masks, hoisted to sgpr-pair vcc by compiler
    const bool ge1 = (j >= 1), ge2 = (j >= 2), ge3 = (j >= 3), ge4 = (j >= 4),
               ge5 = (j >= 5), ge6 = (j >= 6), ge7 = (j >= 7);

    float hj = W_h0[(j < Hn) ? j : 6];

    const float* xb = x + (long long)b * (Tn * INn);
    float* om  = out + (long long)b * (Tn * 3);
    float* orr = out + OFF_OR + (long long)b * Tn;
    float* ring = &lds_r[sm * RSTR];

    // flush read offsets: instr i, lane l -> output dword q=i*16+l,
    // ring addr (q%3)*40 + q/3  (banks distinct: 8*(q%3)+q/3)
    int fq[3];
    #pragma unroll
    for (int i = 0; i < 3; ++i) {
        const int q = i * 16 + l;
        fq[i] = (q % 3) * 40 + q / 3;
    }
    const float* ringA = &lds_r[(2 * g) * RSTR];
    const float* ringB = &lds_r[(2 * g + 1) * RSTR];
    float* omA = out + (long long)(blockIdx.x * BPB + 2 * g) * (Tn * 3);
    float* omB = omA + Tn * 3;
    float* orA = out + OFF_OR + (long long)(blockIdx.x * BPB + 2 * g) * Tn;
    float* orB = orA + Tn;

    // staging role: 8 threads per batch slot (u = lane&7 within slot sm)
    const int u = tid & 7;

    // ---- prologue: stage tile 0 (80 floats = 40 float2 per batch) ----
    float2 stage[5];
    #pragma unroll
    for (int i = 0; i < 5; ++i)
        stage[i] = *(const float2*)(xb + 2 * (u + 8 * i));

    int cur = 0;
    for (int tl = 0; tl < NTILE; ++tl) {
        #pragma unroll
        for (int i = 0; i < 5; ++i)
            *(float2*)&lds_x[cur][sm * XSTR + 2 * (u + 8 * i)] = stage[i];
        __syncthreads();

        if (tl + 1 < NTILE) {
            const float* src = xb + (tl + 1) * (TILE * INn);
            #pragma unroll
            for (int i = 0; i < 5; ++i)
                stage[i] = *(const float2*)(src + 2 * (u + 8 * i));
        }

        // x chunks (4 steps = 5 float4), register double-buffered
        const float4* xq = (const float4*)&lds_x[cur][sm * XSTR];
        float4 xbuf[2][5];
        #pragma unroll
        for (int k = 0; k < 5; ++k) xbuf[0][k] = xq[k];

        #pragma unroll
        for (int c = 0; c < CPT; ++c) {
            if (c + 1 < CPT) {
                #pragma unroll
                for (int k = 0; k < 5; ++k)
                    xbuf[(c + 1) & 1][k] = xq[(c + 1) * 5 + k];
            }
            const float* xcf = (const float*)xbuf[c & 1];

            #pragma unroll
            for (int ss = 0; ss < 4; ++ss) {
                const int tt = c * 4 + ss;     // 0..15 compile-time

                // de-mirrored systolic rotation, two acc chains for ILP
                v2f aczA = biasRZ, aczB = (v2f){0.0f, 0.0f};
                float anA = biasNh, anB = 0.0f;
                aczA = pk_fma(wrz[0], splat2(hj), aczA);
                anA  = fmaf(wn[0], hj, anA);
                #define ROT(i, GE, CA, CB, ACZ, AN)                        \
                {                                                          \
                    float ra = dppf<CA>(hj);                               \
                    float rb = dppf<CB>(hj);                               \
                    float hv = GE ? ra : rb;                               \
                    ACZ = pk_fma(wrz[i], splat2(hv), ACZ);                 \
                    AN  = fmaf(wn[i], hv, AN);                             \
                }
                ROT(1, ge1, 0x121, 0x129, aczB, anB)
                ROT(2, ge2, 0x122, 0x12A, aczA, anA)
                ROT(3, ge3, 0x123, 0x12B, aczB, anB)
                ROT(4, ge4, 0x124, 0x12C, aczA, anA)
                ROT(5, ge5, 0x125, 0x12D, aczB, anB)
                ROT(6, ge6, 0x126, 0x12E, aczA, anA)
                ROT(7, ge7, 0x127, 0x12F, aczB, anB)
                #undef ROT
                v2f acz = aczA + aczB;       // (r_pre_h, z_pre_h) | (m0,m1)
                float an = anA + anB;        // n hidden part      | m2

                // input projection (zeroed on pad lanes)
                v2f pxy = (v2f){0.0f, 0.0f};
                float pn = biasNx;
                #pragma unroll
                for (int i = 0; i < INn; ++i) {
                    pxy = pk_fma(wpx[i], splat2(xcf[5 * ss + i]), pxy);
                    pn  = fmaf(wpn[i], xcf[5 * ss + i], pn);
                }

                // r-head: pure-DPP 8-lane reduce of W_r[j]*h_j (entry h)
                float rr = wrl * hj;
                rr += dppf<0xB1>(rr);        // quad_perm xor1
                rr += dppf<0x4E>(rr);        // quad_perm xor2
                rr += dppf<0x141>(rr);       // row_half_mirror (cross-quad)
                // deferred heads -> ring slot tt (output index tl*16+tt-1)
                if (pad) {
                    ring[tt]      = acz[0];  // m0
                    ring[40 + tt] = acz[1];  // m1
                }
                {   // one instr: pad lanes write m2, j==0 lanes write r
                    const bool w = pad || (j == 0);
                    float v = pad ? an : (rr + brv);
                    if (w) ring[(pad ? 80 : 120) + tt] = v;
                }

                // gates (pad lanes: bounded garbage, never consumed)
                v2f pre = acz + pxy;         // pre-scaled by -log2e
                float er = __builtin_amdgcn_exp2f(pre[0]);
                float ez = __builtin_amdgcn_exp2f(pre[1]);
                float sr = __builtin_amdgcn_rcpf(1.0f + er);
                float sz = __builtin_amdgcn_rcpf(1.0f + ez);
                float pnf = fmaf(sr, an, pn);    // pre-scaled by -2log2e
                float et = __builtin_amdgcn_exp2f(pnf);
                float t  = __builtin_amdgcn_rcpf(1.0f + et);
                float n  = fmaf(2.0f, t, -1.0f); // tanh
                hj = fmaf(sz, hj - n, n);        // (1-z)*n + z*h
            }
        }

        // ---- flush ring -> global (same-wave LDS ordering, no barrier) ----
        {
            float* omtA = omA + tl * 48 - 3;
            float* omtB = omB + tl * 48 - 3;
            #pragma unroll
            for (int i = 0; i < 3; ++i) {
                float vA = ringA[fq[i]];
                float vB = ringB[fq[i]];
                if (tl > 0 || i > 0 || l >= 3) {
                    omtA[i * 16 + l] = vA;
                    omtB[i * 16 + l] = vB;
                }
            }
            float rA = ringA[120 + l];
            float rB = ringB[120 + l];
            if (tl > 0 || l > 0) {
                orA[tl * 16 - 1 + l] = rA;
                orB[tl * 16 - 1 + l] = rB;
            }
        }
        cur ^= 1;
    }

    // ---- epilogue: heads of final h -> index T-1 ----
    {
        v2f aczA = biasRZ, aczB = (v2f){0.0f, 0.0f};
        float anA = biasNh, anB = 0.0f;
        aczA = pk_fma(wrz[0], splat2(hj), aczA);
        anA  = fmaf(wn[0], hj, anA);
        #define ROT(i, GE, CA, CB, ACZ, AN)                        \
        {                                                          \
            float ra = dppf<CA>(hj);                               \
            float rb = dppf<CB>(hj);                               \
            float hv = GE ? ra : rb;                               \
            ACZ = pk_fma(wrz[i], splat2(hv), ACZ);                 \
            AN  = fmaf(wn[i], hv, AN);                             \
        }
        ROT(1, ge1, 0x121, 0x129, aczB, anB)
        ROT(2, ge2, 0x122, 0x12A, aczA, anA)
        ROT(3, ge3, 0x123, 0x12B, aczB, anB)
        ROT(4, ge4, 0x124, 0x12C, aczA, anA)
        ROT(5, ge5, 0x125, 0x12D, aczB, anB)
        ROT(6, ge6, 0x126, 0x12E, aczA, anA)
        ROT(7, ge7, 0x127, 0x12F, aczB, anB)
        #undef ROT
        v2f acz = aczA + aczB;
        float an = anA + anB;
        float rr = wrl * hj;
        rr += dppf<0xB1>(rr);
        rr += dppf<0x4E>(rr);
        rr += dppf<0x141>(rr);
        if (pad) {
            om[(Tn - 1) * 3 + 0] = acz[0];
            om[(Tn - 1) * 3 + 1] = acz[1];
            om[(Tn - 1) * 3 + 2] = an;
        }
        if (j == 0) orr[Tn - 1] = rr + brv;
    }

    // h_last: [1, B, H]
    if (j < Hn) out[OFF_HL + (long long)b * Hn + j] = hj;
}

extern "C" void kernel_launch(void* const* d_in, const int* in_sizes, int n_in,
                              void* d_out, int out_size, void* d_ws, size_t ws_size,
                              hipStream_t stream) {
    const float* x    = (const float*)d_in[0];
    // d_in[1] = batch_size (scalar), unused — B compiled in
    const float* W_ih = (const float*)d_in[2];
    const float* W_hh = (const float*)d_in[3];
    const float* b_ih = (const float*)d_in[4];
    const float* b_hh = (const float*)d_in[5];
    const float* W_h0 = (const float*)d_in[6];
    const float* W_m  = (const float*)d_in[7];
    const float* b_m  = (const float*)d_in[8];
    const float* W_r  = (const float*)d_in[9];
    const float* b_r  = (const float*)d_in[10];
    float* out = (float*)d_out;

    dim3 grid(Bn / BPB);  // 256 blocks = 1 per CU
    dim3 block(256);      // 16 groups x 16 lanes, 2 batches per group
    gru_fused_kernel<<<grid, block, 0, stream>>>(x, W_ih, W_hh, b_ih, b_hh,
                                                 W_h0, W_m, b_m, W_r, b_r, out);
}

// Round 10
// 221.892 us; speedup vs baseline: 1.0948x; 1.0948x over previous
//
#include <hip/hip_runtime.h>

// GRU: B=8192 chains, T=512 steps, IN=5, H=7, fused heads.
// R12 = R10 (114us, VALUBusy 64%) with two zero-risk stall removals.
// R11 lesson (136us, VALUBusy 51%): de-mirror costs 2dpp+sel per rotation,
// issue/batch ~unchanged, and 1 wave/SIMD eats every stall alone. The R10
// mirror layout (16 lanes/batch, 4 batches/wave, 2 waves/SIMD) is the
// keeper: every wave instr serves 4 batches.
// R12 changes vs R10:
//  (1) __syncthreads() DELETED: all LDS traffic (x slab, head ring) is
//      written and read by the same 16-lane group of the same wave; DS ops
//      of a wave execute in order, compiler lgkmcnt handles RAW. The
//      barrier only lockstepped 4 waves' vmcnt/lgkmcnt drains 16x/kernel.
//  (2) head-ring bank fix: HSTR 132->136 (mod32=8), planes m0@0,m1@34,
//      m2@68,r@102 (mod32=0,2,4,6). Per wave the 16 ring writes hit banks
//      8g+tt+{0,2,4,6} -- all distinct (R10's stride-33 planes were ==1
//      mod 32 -> 3 lanes/bank on flush, 1.7M conflict cycles).
// R10 (verified): per-step scattered head stores -> ds_write2 into ring,
// coalesced flush per 32-step tile; head ptr bumps replaced by imm offsets.
// R9 (verified): gate pre-scaling: slot0 rows/biases by -log2e, slot1 by
// -2log2e -> exp2 feed muls gone. R7 (verified): head rows (W_m x3, W_r)
// ride pad lanes l=7,15 of the packed whh pk_fma rotation; head of h_{s-1}
// surfaces at step s -> output index s-1; epilogue does index 511.
// Layout (R4/R5, verified): 16 lanes/batch, lane l: slot0 = r row (l<8) /
// z row (l>=8), slot1 = n row (both halves); one sigmoid/lane + ror:8 swap.
// DPP anchor (R3-R11 passed): row_ror:N dst[n]=src[(n-N)mod16]; position i
// holds unit (l-i)&7; weight k=(j-i)&7, k==7 -> 0 (pad-sourced killed).
// LDS x banks (R4): (g*164+w)%32=(4g+w)%32 -> groups of a wave occupy
// disjoint 4-dword bank ranges per b128 read.

namespace {
constexpr int Bn = 8192;
constexpr int Tn = 512;
constexpr int INn = 5;
constexpr int Hn = 7;
constexpr int TILE = 32;
constexpr int NTILE = Tn / TILE;         // 16
constexpr int BPB = 16;                  // batches per block (256 thr / 16)
constexpr int XSTR = 164;                // padded floats/batch in LDS (x)
constexpr int HSTR = 136;                // head ring: m0@0,m1@34,m2@68,r@102
constexpr long long OFF_OR = (long long)Bn * Tn * 3;
constexpr long long OFF_HL = OFF_OR + (long long)Bn * Tn;
constexpr float LOG2E = 1.44269504088896340736f;
}

typedef float v2f __attribute__((ext_vector_type(2)));

__device__ __forceinline__ v2f pk_fma(v2f a, v2f b, v2f c) {
    return __builtin_elementwise_fma(a, b, c);
}
__device__ __forceinline__ v2f splat2(float x) { return (v2f){x, x}; }

template<int CTRL>
__device__ __forceinline__ float dppf(float v) {
    int r = __builtin_amdgcn_update_dpp(0, __builtin_bit_cast(int, v),
                                        CTRL, 0xF, 0xF, true);
    return __builtin_bit_cast(float, r);
}

__global__ __launch_bounds__(256, 2) void gru_fused_kernel(
    const float* __restrict__ x,     // [B, T, IN]
    const float* __restrict__ W_ih,  // [21, 5]
    const float* __restrict__ W_hh,  // [21, 7]
    const float* __restrict__ b_ih,  // [21]
    const float* __restrict__ b_hh,  // [21]
    const float* __restrict__ W_h0,  // [7, 1]
    const float* __restrict__ W_m,   // [3, 7]
    const float* __restrict__ b_m,   // [3]
    const float* __restrict__ W_r,   // [1, 7]
    const float* __restrict__ b_r,   // [1]
    float* __restrict__ out)
{
    __shared__ float lds_x[2][BPB * XSTR];   // 2 x 10.25 KB
    __shared__ float lds_h[BPB * HSTR];      // 8.5 KB head ring

    const int tid  = threadIdx.x;
    const int l    = tid & 15;           // lane within 16-lane batch group
    const int j    = l & 7;              // hidden-unit slot (7 = pad/head lane)
    const int g    = tid >> 4;           // batch slot in block
    const int b    = blockIdx.x * BPB + g;
    const int jj   = (j < 7) ? j : 6;
    const bool lo8 = ((l & 8) == 0);
    const bool hl  = (j == 7);           // head lanes: l == 7 and l == 15
    const bool is15 = hl && !lo8;        // lane 15

    const float kR = -LOG2E;             // slot0 scale (sigmoid preact)
    const float kN = -2.0f * LOG2E;      // slot1 scale (tanh preact)

    // ---- rotated, packed weights ----
    // matvec lanes (j<7): slot0 = r row (lo8) / z row (hi8) [scaled kR],
    //                     slot1 = n row [scaled kN].
    // head lanes (j==7): l=7  -> slot0 = W_m row0, slot1 = W_m row1
    //                    l=15 -> slot0 = W_m row2, slot1 = W_r   (raw)
    const int row0 = lo8 ? jj : (Hn + jj);
    const int row1 = 2 * Hn + jj;

    v2f whh_rot[8];
    #pragma unroll
    for (int i = 0; i < 8; ++i) {
        const int k = (j - i) & 7;
        if (k < 7) {
            if (hl) {
                const float w0 = lo8 ? W_m[0 * Hn + k] : W_m[2 * Hn + k];
                const float w1 = lo8 ? W_m[1 * Hn + k] : W_r[k];
                whh_rot[i] = (v2f){w0, w1};
            } else {
                whh_rot[i] = (v2f){kR * W_hh[row0 * Hn + k],
                                   kN * W_hh[row1 * Hn + k]};
            }
        } else {
            whh_rot[i] = (v2f){0.0f, 0.0f};
        }
    }
    v2f wih01[INn];
    #pragma unroll
    for (int i = 0; i < INn; ++i)
        wih01[i] = hl ? (v2f){0.0f, 0.0f}
                      : (v2f){kR * W_ih[row0 * INn + i],
                              kN * W_ih[row1 * INn + i]};
    const v2f biasH = hl ? (lo8 ? (v2f){b_m[0], b_m[1]}
                                : (v2f){b_m[2], b_r[0]})
                         : (v2f){kR * b_hh[row0], kN * b_hh[row1]};
    const v2f biasP = hl ? (v2f){0.0f, 0.0f}
                         : (v2f){kR * b_ih[row0], kN * b_ih[row1]};

    float hj = W_h0[jj];

    const float* xb = x + (long long)b * (Tn * INn);
    float* om  = out + (long long)b * (Tn * 3);
    float* orr = out + OFF_OR + (long long)b * Tn;

    // head buffer bases + flush read offsets (all tile-invariant)
    float* hwb = &lds_h[g * HSTR + (is15 ? 68 : 0)];   // writer (lanes 7/15)
    const float* hrd = &lds_h[g * HSTR];               // flush reader
    int fq[6];
    #pragma unroll
    for (int i = 0; i < 6; ++i) {
        const int q = i * 16 + l;                      // output dword 0..95
        fq[i] = (q % 3) * 34 + q / 3;                  // planar -> interleaved
    }

    // ---- prologue: stage tile 0 (160 floats = 80 float2 per batch) ----
    float2 stage[5];
    #pragma unroll
    for (int i = 0; i < 5; ++i)
        stage[i] = *(const float2*)(xb + 2 * (l + 16 * i));

    int cur = 0;
    for (int tl = 0; tl < NTILE; ++tl) {
        // own-group LDS region, own wave: DS in-order per wave -> no barrier
        #pragma unroll
        for (int i = 0; i < 5; ++i)
            *(float2*)&lds_x[cur][g * XSTR + 2 * (l + 16 * i)] = stage[i];

        if (tl + 1 < NTILE) {
            const float* src = xb + (tl + 1) * (TILE * INn);
            #pragma unroll
            for (int i = 0; i < 5; ++i)
                stage[i] = *(const float2*)(src + 2 * (l + 16 * i));
        }

        // x for this tile as 8 chunks of 4 steps (20 floats = 5 float4),
        // register double-buffered: chunk c+1 loads issue while c computes.
        const float4* xq = (const float4*)&lds_x[cur][g * XSTR];
        float4 xbuf[2][5];
        #pragma unroll
        for (int k = 0; k < 5; ++k) xbuf[0][k] = xq[k];

        #pragma unroll
        for (int c = 0; c < 8; ++c) {
            if (c < 7) {
                #pragma unroll
                for (int k = 0; k < 5; ++k)
                    xbuf[(c + 1) & 1][k] = xq[(c + 1) * 5 + k];
            }
            const float* xcf = (const float*)xbuf[c & 1];

            #pragma unroll
            for (int ss = 0; ss < 4; ++ss) {
                const int tt = c * 4 + ss;     // 0..31, compile-time

                // systolic rotation: hidden matvec (packed r|z, n) and the
                // head rows (pad lanes) share one pk_fma chain.
                v2f accA = biasH;
                v2f accB = (v2f){0.0f, 0.0f};
                accA = pk_fma(whh_rot[0], splat2(hj), accA);
                {
                    float h1 = dppf<0x121>(hj);
                    accB = pk_fma(whh_rot[1], splat2(h1), accB);
                    float h2 = dppf<0x122>(hj);
                    accA = pk_fma(whh_rot[2], splat2(h2), accA);
                    float h3 = dppf<0x123>(hj);
                    accB = pk_fma(whh_rot[3], splat2(h3), accB);
                    float h4 = dppf<0x124>(hj);
                    accA = pk_fma(whh_rot[4], splat2(h4), accA);
                    float h5 = dppf<0x125>(hj);
                    accB = pk_fma(whh_rot[5], splat2(h5), accB);
                    float h6 = dppf<0x126>(hj);
                    accA = pk_fma(whh_rot[6], splat2(h6), accA);
                    float h7 = dppf<0x127>(hj);
                    accB = pk_fma(whh_rot[7], splat2(h7), accB);
                }
                v2f accH = accA + accB;      // matvec lanes: (g0,g1) scaled
                                             // head lanes: (head0, head1) raw

                // input projection (zeroed on head lanes)
                v2f accP = biasP;
                #pragma unroll
                for (int i = 0; i < INn; ++i)
                    accP = pk_fma(wih01[i], splat2(xcf[5 * ss + i]), accP);

                // head(h_{s-1}) -> LDS ring slot tt (output index tl*32+tt-1);
                // offsets are compile-time -> single ds_write2_b32.
                if (hl) {
                    hwb[tt]      = accH[0];
                    hwb[34 + tt] = accH[1];
                }

                // gates: preacts arrive pre-scaled by -log2e / -2log2e
                float ea = __builtin_amdgcn_exp2f(accH[0] + accP[0]);
                float s  = __builtin_amdgcn_rcpf(1.0f + ea);
                float sv = dppf<0x128>(s);       // row_ror:8 half-swap
                float rv = lo8 ? s : sv;
                float zv = lo8 ? sv : s;
                float et = __builtin_amdgcn_exp2f(fmaf(rv, accH[1], accP[1]));
                float t  = __builtin_amdgcn_rcpf(1.0f + et);
                float n  = fmaf(2.0f, t, -1.0f); // tanh
                hj = n + zv * (hj - n);          // (1-z)*n + z*h
            }
        }

        // ---- flush head ring: output indices tl*32-1 .. tl*32+30 ----
        // same-wave LDS ordering: writes above are older, reads here wait
        // lgkmcnt; next tile's writes are newer. Coalesced stores: instr i
        // writes 16 consecutive dwords per group.
        {
            float* omt = om + tl * 96 - 3;
            float* ort = orr + tl * 32 - 1;
            #pragma unroll
            for (int i = 0; i < 6; ++i) {
                float v = hrd[fq[i]];
                if (tl > 0 || i > 0 || l >= 3) omt[i * 16 + l] = v;
            }
            float v0 = hrd[102 + l];
            float v1 = hrd[102 + 16 + l];
            if (tl > 0 || l > 0) ort[l] = v0;
            ort[16 + l] = v1;
        }
        cur ^= 1;
    }

    // epilogue: head of final h (one more rotation), stored at index T-1
    {
        v2f accA = biasH;
        v2f accB = (v2f){0.0f, 0.0f};
        accA = pk_fma(whh_rot[0], splat2(hj), accA);
        accB = pk_fma(whh_rot[1], splat2(dppf<0x121>(hj)), accB);
        accA = pk_fma(whh_rot[2], splat2(dppf<0x122>(hj)), accA);
        accB = pk_fma(whh_rot[3], splat2(dppf<0x123>(hj)), accB);
        accA = pk_fma(whh_rot[4], splat2(dppf<0x124>(hj)), accA);
        accB = pk_fma(whh_rot[5], splat2(dppf<0x125>(hj)), accB);
        accA = pk_fma(whh_rot[6], splat2(dppf<0x126>(hj)), accA);
        accB = pk_fma(whh_rot[7], splat2(dppf<0x127>(hj)), accB);
        v2f accH = accA + accB;
        if (hl)  om[(Tn - 1) * 3 + (lo8 ? 0 : 2)] = accH[0];
        if (hl && lo8) om[(Tn - 1) * 3 + 1] = accH[1];
        if (is15)      orr[Tn - 1]          = accH[1];
    }

    // h_last: [1, B, H]
    if (l < Hn) out[OFF_HL + (long long)b * Hn + l] = hj;
}

extern "C" void kernel_launch(void* const* d_in, const int* in_sizes, int n_in,
                              void* d_out, int out_size, void* d_ws, size_t ws_size,
                              hipStream_t stream) {
    const float* x    = (const float*)d_in[0];
    // d_in[1] = batch_size (scalar), unused — B compiled in
    const float* W_ih = (const float*)d_in[2];
    const float* W_hh = (const float*)d_in[3];
    const float* b_ih = (const float*)d_in[4];
    const float* b_hh = (const float*)d_in[5];
    const float* W_h0 = (const float*)d_in[6];
    const float* W_m  = (const float*)d_in[7];
    const float* b_m  = (const float*)d_in[8];
    const float* W_r  = (const float*)d_in[9];
    const float* b_r  = (const float*)d_in[10];
    float* out = (float*)d_out;

    dim3 grid(Bn / BPB);  // 512 blocks
    dim3 block(256);      // 16 batch elements x 16 lanes
    gru_fused_kernel<<<grid, block, 0, stream>>>(x, W_ih, W_hh, b_ih, b_hh,
                                                 W_h0, W_m, b_m, W_r, b_r, out);
}